// Round 1
// baseline (917.066 us; speedup 1.0000x reference)
//
#include <hip/hip_runtime.h>
#include <hip/hip_bf16.h>

// Problem constants: B=32, NUM=512, FEAT=1024, H=8, HLEN=128
typedef __attribute__((ext_vector_type(8))) short s8v;   // 8 bf16 = one MFMA operand frag
typedef __attribute__((ext_vector_type(4))) float f4v;   // MFMA accumulator
typedef __hip_bfloat16 bf16;

__device__ __forceinline__ unsigned short f2b(float f) {
  bf16 h = __float2bfloat16(f);
  return *reinterpret_cast<unsigned short*>(&h);
}

// ---------------- gate: g2s[b][f] = (mean_n x2[b,n,f])^2 / sqrt(128) -------------
__global__ __launch_bounds__(256) void gate_kernel(const float* __restrict__ x2,
                                                   float* __restrict__ g2s) {
  __shared__ float red[256];
  const int b = blockIdx.x >> 4, fc = blockIdx.x & 15;
  const int fi = threadIdx.x & 63, ng = threadIdx.x >> 6;
  const int f = fc * 64 + fi;
  const float* p = x2 + (size_t)b * 524288 + f;
  float s = 0.f;
  for (int n = ng * 128; n < ng * 128 + 128; ++n) s += p[(size_t)n * 1024];
  red[threadIdx.x] = s;
  __syncthreads();
  if (threadIdx.x < 64) {
    float tot = red[fi] + red[fi + 64] + red[fi + 128] + red[fi + 192];
    float mean = tot * (1.0f / 512.0f);
    g2s[b * 1024 + f] = mean * mean * 0.08838834764831845f; // 1/sqrt(128)
  }
}

// ---------------- x1 f32 -> bf16 copy (vectorized) -------------------------------
__global__ __launch_bounds__(256) void cvt_f32_bf16(const float* __restrict__ in,
                                                    bf16* __restrict__ out, int n4) {
  int i = blockIdx.x * 256 + threadIdx.x;
  if (i >= n4) return;
  f4v v = reinterpret_cast<const f4v*>(in)[i];
  ushort4 o;
  o.x = f2b(v.x); o.y = f2b(v.y); o.z = f2b(v.z); o.w = f2b(v.w);
  reinterpret_cast<ushort4*>(out)[i] = o;
}

// ---------------- generic 32x32-tiled transpose f32 -> bf16 ----------------------
// in: [batch][R][C] (row stride in_rstride), out: [batch][C][R] (row stride out_rstride)
__global__ __launch_bounds__(256) void transpose_f32_bf16(
    const float* __restrict__ in, bf16* __restrict__ out,
    int in_rstride, int out_rstride, int hi_shift,
    long hi_mul, long lo_mul, long out_mul) {
  __shared__ float tile[32][33];
  const int z = blockIdx.z;
  const long in_off = (long)(z >> hi_shift) * hi_mul + (long)(z & ((1 << hi_shift) - 1)) * lo_mul;
  const int r0 = blockIdx.x * 32, c0 = blockIdx.y * 32;
  const int i = threadIdx.x >> 5, j = threadIdx.x & 31;
  const float* ip = in + in_off + (long)r0 * in_rstride + c0;
#pragma unroll
  for (int s = 0; s < 4; ++s) tile[i + s * 8][j] = ip[(long)(i + s * 8) * in_rstride + j];
  __syncthreads();
  bf16* op = out + (long)z * out_mul + (long)c0 * out_rstride + r0;
#pragma unroll
  for (int s = 0; s < 4; ++s) op[(long)(i + s * 8) * out_rstride + j] = __float2bfloat16(tile[j][i + s * 8]);
}

// ---------------- GEMM-NT template: C[MxN] = A[MxK] * BT[NxK]^T ------------------
// EPI 0: Qs = bf16((acc + bq[col]) * g2s[b][col])           (A bf16)
// EPI 1: V_ = bf16(acc), batched per (b,h), out offset      (A f32 = att)
// EPI 2: out = relu(acc + bl[col]) + x1[row,col]  (f32)     (A bf16)
template <int EPI>
__global__ __launch_bounds__(256) void gemm_nt(
    const void* __restrict__ Ap, const bf16* __restrict__ BTp, void* __restrict__ Op,
    const float* __restrict__ e1, const float* __restrict__ e2,
    int K, int lda, int ldb) {
  constexpr bool AF32 = (EPI == 1);
  __shared__ alignas(16) bf16 As[128 * 40];
  __shared__ alignas(16) bf16 Bs[128 * 40];
  const int t = threadIdx.x;
  const int lane = t & 63;
  const int w = t >> 6;
  const int wr = w >> 1, wc = w & 1;
  const int lr = lane & 15, g = lane >> 4;
  const int z = blockIdx.z;
  const int m0 = blockIdx.x * 128, n0 = blockIdx.y * 128;

  const bf16* Ab = nullptr;
  const float* Af = nullptr;
  const bf16* BT = BTp;
  if constexpr (AF32) {
    Af = reinterpret_cast<const float*>(Ap) + (size_t)z * (512 * 512);
    BT = BTp + (size_t)z * (128 * 512);
  } else {
    Ab = reinterpret_cast<const bf16*>(Ap);
  }

  f4v acc[4][4];
#pragma unroll
  for (int i = 0; i < 4; ++i)
#pragma unroll
    for (int j = 0; j < 4; ++j) acc[i][j] = (f4v){0.f, 0.f, 0.f, 0.f};

  for (int k0 = 0; k0 < K; k0 += 32) {
    __syncthreads();
    if constexpr (AF32) {
#pragma unroll
      for (int i = 0; i < 4; ++i) {
        int c = t + i * 256;          // 1024 float4 chunks (128 rows x 8)
        int r = c >> 3, q = c & 7;
        f4v v = *reinterpret_cast<const f4v*>(Af + (size_t)(m0 + r) * lda + k0 + q * 4);
        ushort4 o;
        o.x = f2b(v.x); o.y = f2b(v.y); o.z = f2b(v.z); o.w = f2b(v.w);
        *reinterpret_cast<ushort4*>(&As[r * 40 + q * 4]) = o;
      }
    } else {
#pragma unroll
      for (int i = 0; i < 2; ++i) {
        int c = t + i * 256;          // 512 16B chunks (128 rows x 4)
        int r = c >> 2, q = c & 3;
        s8v v = *reinterpret_cast<const s8v*>(Ab + (size_t)(m0 + r) * lda + k0 + q * 8);
        *reinterpret_cast<s8v*>(&As[r * 40 + q * 8]) = v;
      }
    }
#pragma unroll
    for (int i = 0; i < 2; ++i) {
      int c = t + i * 256;
      int r = c >> 2, q = c & 3;
      s8v v = *reinterpret_cast<const s8v*>(BT + (size_t)(n0 + r) * ldb + k0 + q * 8);
      *reinterpret_cast<s8v*>(&Bs[r * 40 + q * 8]) = v;
    }
    __syncthreads();
    s8v af[4], bfr[4];
#pragma unroll
    for (int mi = 0; mi < 4; ++mi)
      af[mi] = *reinterpret_cast<const s8v*>(&As[(wr * 64 + mi * 16 + lr) * 40 + g * 8]);
#pragma unroll
    for (int ni = 0; ni < 4; ++ni)
      bfr[ni] = *reinterpret_cast<const s8v*>(&Bs[(wc * 64 + ni * 16 + lr) * 40 + g * 8]);
#pragma unroll
    for (int mi = 0; mi < 4; ++mi)
#pragma unroll
      for (int ni = 0; ni < 4; ++ni)
        acc[mi][ni] = __builtin_amdgcn_mfma_f32_16x16x32_bf16(af[mi], bfr[ni], acc[mi][ni], 0, 0, 0);
  }

#pragma unroll
  for (int mi = 0; mi < 4; ++mi) {
#pragma unroll
    for (int ni = 0; ni < 4; ++ni) {
#pragma unroll
      for (int v = 0; v < 4; ++v) {
        int row = m0 + wr * 64 + mi * 16 + g * 4 + v;
        int col = n0 + wc * 64 + ni * 16 + lr;
        float val = acc[mi][ni][v];
        if constexpr (EPI == 0) {
          float q = (val + e1[col]) * e2[(row >> 9) * 1024 + col];
          reinterpret_cast<bf16*>(Op)[(size_t)row * 1024 + col] = __float2bfloat16(q);
        } else if constexpr (EPI == 1) {
          int b = z >> 3, h = z & 7;
          reinterpret_cast<bf16*>(Op)[((size_t)(b * 512 + row)) * 1024 + h * 128 + col] =
              __float2bfloat16(val);
        } else {
          float r2 = fmaxf(val + e1[col], 0.f) + e2[(size_t)row * 1024 + col];
          reinterpret_cast<float*>(Op)[(size_t)row * 1024 + col] = r2;
        }
      }
    }
  }
}

// ---------------- fused scores + mask + softmax ----------------------------------
// 1 wave per block; block = (b,h, 16-row strip). Scores strip 16x512 kept in VGPRs.
__global__ __launch_bounds__(64) void attn_softmax(
    const bf16* __restrict__ Qs, const bf16* __restrict__ x1b,
    const int* __restrict__ mask, float* __restrict__ att) {
  const int bid = blockIdx.x;
  const int rt = bid & 31;
  const int bh = bid >> 5;
  const int h = bh & 7, b = bh >> 3;
  const int lane = threadIdx.x;
  const int lr = lane & 15, g = lane >> 4;
  const int n0 = rt * 16;

  const bf16* qrow = Qs + (size_t)(b * 512 + n0 + lr) * 1024 + h * 128;
  s8v a[4];
#pragma unroll
  for (int kt = 0; kt < 4; ++kt) a[kt] = *reinterpret_cast<const s8v*>(qrow + kt * 32 + g * 8);

  f4v acc[32];
#pragma unroll
  for (int mt = 0; mt < 32; ++mt) acc[mt] = (f4v){0.f, 0.f, 0.f, 0.f};

  const bf16* kbase = x1b + (size_t)b * 512 * 1024 + h * 128;
#pragma unroll
  for (int mt = 0; mt < 32; ++mt) {
    const bf16* krow = kbase + (size_t)(mt * 16 + lr) * 1024;
#pragma unroll
    for (int kt = 0; kt < 4; ++kt) {
      s8v bb = *reinterpret_cast<const s8v*>(krow + kt * 32 + g * 8);
      acc[mt] = __builtin_amdgcn_mfma_f32_16x16x32_bf16(a[kt], bb, acc[mt], 0, 0, 0);
    }
  }

  // lane holds rows g*4+v (v=0..3), cols mt*16+lr
  const int* mrow = mask + (size_t)b * 512 * 512 + (size_t)n0 * 512;
  float mx[4] = {-3e38f, -3e38f, -3e38f, -3e38f};
#pragma unroll
  for (int mt = 0; mt < 32; ++mt) {
#pragma unroll
    for (int v = 0; v < 4; ++v) {
      int row = g * 4 + v, col = mt * 16 + lr;
      float val = acc[mt][v];
      val = mrow[row * 512 + col] ? -1e9f : val;
      acc[mt][v] = val;
      mx[v] = fmaxf(mx[v], val);
    }
  }
#pragma unroll
  for (int v = 0; v < 4; ++v) {
    float m = mx[v];
    m = fmaxf(m, __shfl_xor(m, 1));
    m = fmaxf(m, __shfl_xor(m, 2));
    m = fmaxf(m, __shfl_xor(m, 4));
    m = fmaxf(m, __shfl_xor(m, 8));
    mx[v] = m;
  }
  float sm[4] = {0.f, 0.f, 0.f, 0.f};
#pragma unroll
  for (int mt = 0; mt < 32; ++mt) {
#pragma unroll
    for (int v = 0; v < 4; ++v) {
      float e = __expf(acc[mt][v] - mx[v]);
      acc[mt][v] = e;
      sm[v] += e;
    }
  }
#pragma unroll
  for (int v = 0; v < 4; ++v) {
    float s = sm[v];
    s += __shfl_xor(s, 1);
    s += __shfl_xor(s, 2);
    s += __shfl_xor(s, 4);
    s += __shfl_xor(s, 8);
    sm[v] = 1.0f / s;
  }
  float* orow = att + ((size_t)bh * 512 + n0) * 512;
#pragma unroll
  for (int mt = 0; mt < 32; ++mt) {
#pragma unroll
    for (int v = 0; v < 4; ++v) {
      orow[(g * 4 + v) * 512 + mt * 16 + lr] = acc[mt][v] * sm[v];
    }
  }
}

extern "C" void kernel_launch(void* const* d_in, const int* in_sizes, int n_in,
                              void* d_out, int out_size, void* d_ws, size_t ws_size,
                              hipStream_t stream) {
  (void)in_sizes; (void)n_in; (void)out_size; (void)ws_size;
  const float* x1 = (const float*)d_in[0];
  const float* x2 = (const float*)d_in[1];
  // d_in[2]=adj, d_in[3]=bias are unused by the reference forward
  const int* mask = (const int*)d_in[4];
  const float* Wq = (const float*)d_in[5];
  const float* bq = (const float*)d_in[6];
  const float* Wl = (const float*)d_in[7];
  const float* bl = (const float*)d_in[8];

  float* xout = (float*)d_out;                  // [32,512,1024]
  float* att = (float*)d_out + 16777216;        // [32,8,512,512]

  char* ws = (char*)d_ws;
  bf16* x1b   = (bf16*)(ws);                    // 33.5MB  (later reused as V_ bf16)
  bf16* VT    = (bf16*)(ws + 33554432);         // 33.5MB  [B,H,128,512]
  bf16* Qs    = (bf16*)(ws + 67108864);         // 33.5MB  [B,NUM,FEAT] gated+scaled
  bf16* WcatT = (bf16*)(ws + 100663296);        // 2MB     [n=1024][k=1024]
  bf16* WlT   = (bf16*)(ws + 102760448);        // 2MB     [n=1024][k=1024]
  float* g2s  = (float*)(ws + 104857600);       // 128KB   [B][1024]

  gate_kernel<<<dim3(32 * 16), dim3(256), 0, stream>>>(x2, g2s);
  cvt_f32_bf16<<<dim3(16384), dim3(256), 0, stream>>>(x1, x1b, 4194304);
  // VT[b,h,d,m] = x1[b,m,h*128+d]
  transpose_f32_bf16<<<dim3(16, 4, 256), dim3(256), 0, stream>>>(
      x1, VT, 1024, 512, 3, (long)524288, (long)128, (long)65536);
  // WcatT[h*128+d][f] = Wq[h][f][d]
  transpose_f32_bf16<<<dim3(32, 4, 8), dim3(256), 0, stream>>>(
      Wq, WcatT, 128, 1024, 0, (long)131072, (long)0, (long)131072);
  // WlT[n][k] = Wl[k][n]
  transpose_f32_bf16<<<dim3(32, 32, 1), dim3(256), 0, stream>>>(
      Wl, WlT, 1024, 1024, 0, (long)0, (long)0, (long)0);
  // Qs = (x1 @ Wcat + bq) * g2s   [16384 x 1024 x 1024]
  gemm_nt<0><<<dim3(128, 8, 1), dim3(256), 0, stream>>>(
      (const void*)x1b, WcatT, (void*)Qs, bq, g2s, 1024, 1024, 1024);
  // scores + mask + softmax -> att (f32, to d_out)
  attn_softmax<<<dim3(8192), dim3(64), 0, stream>>>(Qs, x1b, mask, att);
  // V_ = att @ V  (batched per (b,h)), written bf16 into x1b region
  gemm_nt<1><<<dim3(4, 1, 256), dim3(256), 0, stream>>>(
      (const void*)att, VT, (void*)x1b, nullptr, nullptr, 512, 512, 512);
  // xout = relu(V_ @ Wl + bl) + x1
  gemm_nt<2><<<dim3(128, 8, 1), dim3(256), 0, stream>>>(
      (const void*)x1b, WlT, (void*)xout, bl, x1, 1024, 1024, 1024);
}

// Round 2
// 901.807 us; speedup vs baseline: 1.0169x; 1.0169x over previous
//
#include <hip/hip_runtime.h>
#include <hip/hip_bf16.h>

// Problem constants: B=32, NUM=512, FEAT=1024, H=8, HLEN=128
typedef __attribute__((ext_vector_type(8))) short s8v;   // 8 bf16 = one MFMA operand frag
typedef __attribute__((ext_vector_type(4))) float f4v;   // MFMA accumulator
typedef __hip_bfloat16 bf16;

__device__ __forceinline__ unsigned short f2b(float f) {
  bf16 h = __float2bfloat16(f);
  return *reinterpret_cast<unsigned short*>(&h);
}

// async global->LDS, 16B per lane; LDS dest = wave-uniform base + lane*16
__device__ __forceinline__ void gload16(const void* g, void* l) {
  __builtin_amdgcn_global_load_lds(
      (const __attribute__((address_space(1))) void*)g,
      (__attribute__((address_space(3))) void*)l, 16, 0, 0);
}

// ---------------- gate: g2s[b][f] = (mean_n x2[b,n,f])^2 / sqrt(128) -------------
__global__ __launch_bounds__(256) void gate_kernel(const float* __restrict__ x2,
                                                   float* __restrict__ g2s) {
  __shared__ float red[256];
  const int b = blockIdx.x >> 4, fc = blockIdx.x & 15;
  const int fi = threadIdx.x & 63, ng = threadIdx.x >> 6;
  const int f = fc * 64 + fi;
  const float* p = x2 + (size_t)b * 524288 + f;
  float s = 0.f;
  for (int n = ng * 128; n < ng * 128 + 128; ++n) s += p[(size_t)n * 1024];
  red[threadIdx.x] = s;
  __syncthreads();
  if (threadIdx.x < 64) {
    float tot = red[fi] + red[fi + 64] + red[fi + 128] + red[fi + 192];
    float mean = tot * (1.0f / 512.0f);
    g2s[b * 1024 + f] = mean * mean * 0.08838834764831845f; // 1/sqrt(128)
  }
}

// ---------------- x1 f32 -> bf16 copy (vectorized) -------------------------------
__global__ __launch_bounds__(256) void cvt_f32_bf16(const float* __restrict__ in,
                                                    bf16* __restrict__ out, int n4) {
  int i = blockIdx.x * 256 + threadIdx.x;
  if (i >= n4) return;
  f4v v = reinterpret_cast<const f4v*>(in)[i];
  ushort4 o;
  o.x = f2b(v.x); o.y = f2b(v.y); o.z = f2b(v.z); o.w = f2b(v.w);
  reinterpret_cast<ushort4*>(out)[i] = o;
}

// ---------------- generic 32x32-tiled transpose f32 -> bf16 ----------------------
__global__ __launch_bounds__(256) void transpose_f32_bf16(
    const float* __restrict__ in, bf16* __restrict__ out,
    int in_rstride, int out_rstride, int hi_shift,
    long hi_mul, long lo_mul, long out_mul) {
  __shared__ float tile[32][33];
  const int z = blockIdx.z;
  const long in_off = (long)(z >> hi_shift) * hi_mul + (long)(z & ((1 << hi_shift) - 1)) * lo_mul;
  const int r0 = blockIdx.x * 32, c0 = blockIdx.y * 32;
  const int i = threadIdx.x >> 5, j = threadIdx.x & 31;
  const float* ip = in + in_off + (long)r0 * in_rstride + c0;
#pragma unroll
  for (int s = 0; s < 4; ++s) tile[i + s * 8][j] = ip[(long)(i + s * 8) * in_rstride + j];
  __syncthreads();
  bf16* op = out + (long)z * out_mul + (long)c0 * out_rstride + r0;
#pragma unroll
  for (int s = 0; s < 4; ++s) op[(long)(i + s * 8) * out_rstride + j] = __float2bfloat16(tile[j][i + s * 8]);
}

// ---------------- m97-structure GEMM-NT: C[16384x1024] = A[.x1024] * BT[1024x1024]^T
// EPI 0: Qs = bf16((acc + bq[col]) * g2s[b][col])
// EPI 2: out = relu(acc + bl[col]) + x1[row,col]  (f32)
// LDS: linear [128][32] bf16, filled via global_load_lds with PRE-SWIZZLED global
// source (slot q = (i&3) ^ ((i>>3)&3)); read side XORs the same factor -> <=2-way
// bank aliasing on ds_read_b128 (free per m136).
template <int EPI>
__global__ __launch_bounds__(256) void gemm_nt(
    const bf16* __restrict__ A, const bf16* __restrict__ BT, void* __restrict__ Op,
    const float* __restrict__ e1, const float* __restrict__ e2) {
  __shared__ alignas(16) bf16 As[128 * 32];
  __shared__ alignas(16) bf16 Bs[128 * 32];
  const int t = threadIdx.x;
  const int lane = t & 63;
  const int wv = t >> 6;
  const int wr = wv >> 1, wc = wv & 1;
  const int lr = lane & 15, g = lane >> 4;
  // XCD-bijective swizzle: nwg=1024 (div by 8); XCD c owns m-panels [c*16, c*16+16)
  // so its 16 x 256KB A-panels live in its 4MB L2 across all 8 n-blocks.
  const int o = blockIdx.x;
  const int wk = (o & 7) * 128 + (o >> 3);
  const int m0 = (wk >> 3) * 128, n0 = (wk & 7) * 128;

  // staging: 8 chunks of 1KB per tile; wave wv stages chunks 2wv, 2wv+1
  const int cr = lane >> 2;                       // row within 16-row chunk
  const int q = (lane & 3) ^ ((lane >> 3) & 3);   // pre-swizzled 16B slot
  const int c0 = 2 * wv, c1 = 2 * wv + 1;
  const bf16* gA0 = A + (size_t)(m0 + c0 * 16 + cr) * 1024 + q * 8;
  const bf16* gA1 = A + (size_t)(m0 + c1 * 16 + cr) * 1024 + q * 8;
  const bf16* gB0 = BT + (size_t)(n0 + c0 * 16 + cr) * 1024 + q * 8;
  const bf16* gB1 = BT + (size_t)(n0 + c1 * 16 + cr) * 1024 + q * 8;
  bf16* lA0 = &As[c0 * 512]; bf16* lA1 = &As[c1 * 512];
  bf16* lB0 = &Bs[c0 * 512]; bf16* lB1 = &Bs[c1 * 512];

  f4v acc[4][4];
#pragma unroll
  for (int i = 0; i < 4; ++i)
#pragma unroll
    for (int j = 0; j < 4; ++j) acc[i][j] = (f4v){0.f, 0.f, 0.f, 0.f};

  const int xr = (lr >> 1) & 3;  // read-side swizzle factor (lane-constant)

  for (int k0 = 0; k0 < 1024; k0 += 32) {
    __syncthreads();
    gload16(gA0 + k0, lA0);
    gload16(gA1 + k0, lA1);
    gload16(gB0 + k0, lB0);
    gload16(gB1 + k0, lB1);
    __syncthreads();   // compiler emits vmcnt(0) drain before s_barrier
    s8v af[4], bfr[4];
#pragma unroll
    for (int mi = 0; mi < 4; ++mi)
      af[mi] = *reinterpret_cast<const s8v*>(&As[(wr * 64 + mi * 16 + lr) * 32 + ((g ^ xr) * 8)]);
#pragma unroll
    for (int ni = 0; ni < 4; ++ni)
      bfr[ni] = *reinterpret_cast<const s8v*>(&Bs[(wc * 64 + ni * 16 + lr) * 32 + ((g ^ xr) * 8)]);
#pragma unroll
    for (int mi = 0; mi < 4; ++mi)
#pragma unroll
      for (int ni = 0; ni < 4; ++ni)
        acc[mi][ni] = __builtin_amdgcn_mfma_f32_16x16x32_bf16(af[mi], bfr[ni], acc[mi][ni], 0, 0, 0);
  }

#pragma unroll
  for (int mi = 0; mi < 4; ++mi) {
#pragma unroll
    for (int ni = 0; ni < 4; ++ni) {
#pragma unroll
      for (int v = 0; v < 4; ++v) {
        int row = m0 + wr * 64 + mi * 16 + g * 4 + v;
        int col = n0 + wc * 64 + ni * 16 + lr;
        float val = acc[mi][ni][v];
        if constexpr (EPI == 0) {
          float qv = (val + e1[col]) * e2[(row >> 9) * 1024 + col];
          reinterpret_cast<bf16*>(Op)[(size_t)row * 1024 + col] = __float2bfloat16(qv);
        } else {
          float r2 = fmaxf(val + e1[col], 0.f) + e2[(size_t)row * 1024 + col];
          reinterpret_cast<float*>(Op)[(size_t)row * 1024 + col] = r2;
        }
      }
    }
  }
}

// ---------------- fused scores + mask + softmax + PV -----------------------------
// 4 waves/block; block = (b,h, 64-row strip); wave owns 16 rows.
// After softmax, P strip (16x512) goes to LDS (bf16, XOR-swizzled) and PV runs via
// MFMA against VT. V_ output is written IN PLACE over Qs: each Qs sub-slab
// [16 rows][h*128..h*128+128] has exactly one reader (this wave) which writes it
// only after consuming it.
__device__ __forceinline__ int fsw(int r) { return ((r >> 2) | ((r & 1) << 2)); }

__global__ __launch_bounds__(256) void attn_fused(
    const bf16* __restrict__ Qs, const bf16* __restrict__ x1b,
    const bf16* __restrict__ VT, const int* __restrict__ mask,
    float* __restrict__ att, bf16* __restrict__ Vout) {
  __shared__ bf16 P[4][16 * 512];   // 64KB
  const int o = blockIdx.x;                        // 2048 blocks
  const int wk = (o & 7) * 256 + (o >> 3);         // XCD c owns bh in [c*32, c*32+32)
  const int rt = wk & 7, bh = wk >> 3;
  const int h = bh & 7, b = bh >> 3;
  const int wv = threadIdx.x >> 6;
  const int lane = threadIdx.x & 63;
  const int lr = lane & 15, g = lane >> 4;
  const int n0 = rt * 64 + wv * 16;                // this wave's 16 rows

  // --- QK^T: acc[mt] covers rows n0+g*4+v, cols mt*16+lr ---
  const bf16* qrow = Qs + (size_t)(b * 512 + n0 + lr) * 1024 + h * 128;
  s8v a[4];
#pragma unroll
  for (int kt = 0; kt < 4; ++kt) a[kt] = *reinterpret_cast<const s8v*>(qrow + kt * 32 + g * 8);

  f4v acc[32];
#pragma unroll
  for (int mt = 0; mt < 32; ++mt) acc[mt] = (f4v){0.f, 0.f, 0.f, 0.f};

  const bf16* kbase = x1b + (size_t)b * 524288 + h * 128;
#pragma unroll
  for (int mt = 0; mt < 32; ++mt) {
    const bf16* krow = kbase + (size_t)(mt * 16 + lr) * 1024;
#pragma unroll
    for (int kt = 0; kt < 4; ++kt) {
      s8v bb = *reinterpret_cast<const s8v*>(krow + kt * 32 + g * 8);
      acc[mt] = __builtin_amdgcn_mfma_f32_16x16x32_bf16(a[kt], bb, acc[mt], 0, 0, 0);
    }
  }

  // --- mask + softmax ---
  const int* mrow = mask + (size_t)b * 262144 + (size_t)n0 * 512;
  float mx[4] = {-3e38f, -3e38f, -3e38f, -3e38f};
#pragma unroll
  for (int mt = 0; mt < 32; ++mt) {
#pragma unroll
    for (int v = 0; v < 4; ++v) {
      int row = g * 4 + v, col = mt * 16 + lr;
      float val = acc[mt][v];
      val = mrow[row * 512 + col] ? -1e9f : val;
      acc[mt][v] = val;
      mx[v] = fmaxf(mx[v], val);
    }
  }
#pragma unroll
  for (int v = 0; v < 4; ++v) {
    float m = mx[v];
    m = fmaxf(m, __shfl_xor(m, 1));
    m = fmaxf(m, __shfl_xor(m, 2));
    m = fmaxf(m, __shfl_xor(m, 4));
    m = fmaxf(m, __shfl_xor(m, 8));
    mx[v] = m;
  }
  float sm[4] = {0.f, 0.f, 0.f, 0.f};
#pragma unroll
  for (int mt = 0; mt < 32; ++mt) {
#pragma unroll
    for (int v = 0; v < 4; ++v) {
      float e = __expf(acc[mt][v] - mx[v]);
      acc[mt][v] = e;
      sm[v] += e;
    }
  }
#pragma unroll
  for (int v = 0; v < 4; ++v) {
    float s = sm[v];
    s += __shfl_xor(s, 1);
    s += __shfl_xor(s, 2);
    s += __shfl_xor(s, 4);
    s += __shfl_xor(s, 8);
    sm[v] = 1.0f / s;
  }

  // --- write att (f32, required output) + P strip to LDS (bf16, swizzled) ---
  float* orow = att + ((size_t)bh * 512 + n0) * 512;
  bf16* Pw = P[wv];
#pragma unroll
  for (int mt = 0; mt < 32; ++mt) {
#pragma unroll
    for (int v = 0; v < 4; ++v) {
      int r = g * 4 + v, c = mt * 16 + lr;
      float tv = acc[mt][v] * sm[v];
      orow[r * 512 + c] = tv;
      Pw[r * 512 + (c ^ (fsw(r) * 8))] = __float2bfloat16(tv);
    }
  }

  // --- PV: out[16x128] += P[16x512] * V[512x128], B-frags straight from VT ---
  s8v a2[16];
  const int fx = fsw(lr) * 8;
#pragma unroll
  for (int kt = 0; kt < 16; ++kt)
    a2[kt] = *reinterpret_cast<const s8v*>(&Pw[lr * 512 + ((kt * 32 + g * 8) ^ fx)]);

  const bf16* vbase = VT + (size_t)bh * 65536;
#pragma unroll
  for (int nt = 0; nt < 8; ++nt) {
    f4v oacc = (f4v){0.f, 0.f, 0.f, 0.f};
#pragma unroll
    for (int kt = 0; kt < 16; ++kt) {
      s8v bb = *reinterpret_cast<const s8v*>(vbase + (size_t)(nt * 16 + lr) * 512 + kt * 32 + g * 8);
      oacc = __builtin_amdgcn_mfma_f32_16x16x32_bf16(a2[kt], bb, oacc, 0, 0, 0);
    }
#pragma unroll
    for (int v = 0; v < 4; ++v) {
      Vout[(size_t)(b * 512 + n0 + g * 4 + v) * 1024 + h * 128 + nt * 16 + lr] =
          __float2bfloat16(oacc[v]);
    }
  }
}

extern "C" void kernel_launch(void* const* d_in, const int* in_sizes, int n_in,
                              void* d_out, int out_size, void* d_ws, size_t ws_size,
                              hipStream_t stream) {
  (void)in_sizes; (void)n_in; (void)out_size; (void)ws_size;
  const float* x1 = (const float*)d_in[0];
  const float* x2 = (const float*)d_in[1];
  // d_in[2]=adj, d_in[3]=bias are unused by the reference forward
  const int* mask = (const int*)d_in[4];
  const float* Wq = (const float*)d_in[5];
  const float* bq = (const float*)d_in[6];
  const float* Wl = (const float*)d_in[7];
  const float* bl = (const float*)d_in[8];

  float* xout = (float*)d_out;                  // [32,512,1024]
  float* att = (float*)d_out + 16777216;        // [32,8,512,512]

  char* ws = (char*)d_ws;
  bf16* x1b   = (bf16*)(ws);                    // 33.5MB  K source
  bf16* VT    = (bf16*)(ws + 33554432);         // 33.5MB  [B,H,128,512]
  bf16* Qs    = (bf16*)(ws + 67108864);         // 33.5MB  gated Q; reused in-place as V_
  bf16* WcatT = (bf16*)(ws + 100663296);        // 2MB     [1024][1024]
  bf16* WlT   = (bf16*)(ws + 102760448);        // 2MB     [1024][1024]
  float* g2s  = (float*)(ws + 104857600);       // 128KB   [B][1024]

  gate_kernel<<<dim3(32 * 16), dim3(256), 0, stream>>>(x2, g2s);
  cvt_f32_bf16<<<dim3(16384), dim3(256), 0, stream>>>(x1, x1b, 4194304);
  // VT[b,h,d,m] = x1[b,m,h*128+d]
  transpose_f32_bf16<<<dim3(16, 4, 256), dim3(256), 0, stream>>>(
      x1, VT, 1024, 512, 3, (long)524288, (long)128, (long)65536);
  // WcatT[h*128+d][f] = Wq[h][f][d]
  transpose_f32_bf16<<<dim3(32, 4, 8), dim3(256), 0, stream>>>(
      Wq, WcatT, 128, 1024, 0, (long)131072, (long)0, (long)131072);
  // WlT[n][k] = Wl[k][n]
  transpose_f32_bf16<<<dim3(32, 32, 1), dim3(256), 0, stream>>>(
      Wl, WlT, 1024, 1024, 0, (long)0, (long)0, (long)0);
  // Qs = (x1 @ Wcat + bq) * g2s
  gemm_nt<0><<<dim3(1024), dim3(256), 0, stream>>>(x1b, WcatT, (void*)Qs, bq, g2s);
  // scores + mask + softmax -> att (d_out), then PV -> Vout (in-place over Qs)
  attn_fused<<<dim3(2048), dim3(256), 0, stream>>>(Qs, x1b, VT, mask, att, Qs);
  // xout = relu(V_ @ Wl + bl) + x1
  gemm_nt<2><<<dim3(1024), dim3(256), 0, stream>>>(Qs, WlT, (void*)xout, bl, x1);
}

// Round 4
// 809.619 us; speedup vs baseline: 1.1327x; 1.1139x over previous
//
#include <hip/hip_runtime.h>
#include <hip/hip_bf16.h>

// Problem constants: B=32, NUM=512, FEAT=1024, H=8, HLEN=128
typedef __attribute__((ext_vector_type(8))) short s8v;   // 8 bf16 = one MFMA operand frag
typedef __attribute__((ext_vector_type(4))) float f4v;   // MFMA accumulator
typedef __hip_bfloat16 bf16;

__device__ __forceinline__ unsigned short f2b(float f) {
  bf16 h = __float2bfloat16(f);
  return *reinterpret_cast<unsigned short*>(&h);
}

// async global->LDS, 16B per lane; LDS dest = wave-uniform base + lane*16
__device__ __forceinline__ void gload16(const void* g, void* l) {
  __builtin_amdgcn_global_load_lds(
      (const __attribute__((address_space(1))) void*)g,
      (__attribute__((address_space(3))) void*)l, 16, 0, 0);
}

// ---------------- gate: g2s[b][f] = (mean_n x2[b,n,f])^2 / sqrt(128) -------------
__global__ __launch_bounds__(256) void gate_kernel(const float* __restrict__ x2,
                                                   float* __restrict__ g2s) {
  __shared__ float red[256];
  const int b = blockIdx.x >> 4, fc = blockIdx.x & 15;
  const int fi = threadIdx.x & 63, ng = threadIdx.x >> 6;
  const int f = fc * 64 + fi;
  const float* p = x2 + (size_t)b * 524288 + f;
  float s = 0.f;
  for (int n = ng * 128; n < ng * 128 + 128; ++n) s += p[(size_t)n * 1024];
  red[threadIdx.x] = s;
  __syncthreads();
  if (threadIdx.x < 64) {
    float tot = red[fi] + red[fi + 64] + red[fi + 128] + red[fi + 192];
    float mean = tot * (1.0f / 512.0f);
    g2s[b * 1024 + f] = mean * mean * 0.08838834764831845f; // 1/sqrt(128)
  }
}

// ---------------- fused x1 prep: x1b = bf16(x1); VT[b,h,d,m] = bf16(x1[b,m,h*128+d])
__global__ __launch_bounds__(256) void x1prep(const float* __restrict__ x1,
                                              bf16* __restrict__ x1b,
                                              bf16* __restrict__ VT) {
  __shared__ float tile[32][33];
  const int mt = blockIdx.x;   // 0..15 (m tiles of 32)
  const int ft = blockIdx.y;   // 0..31 (f tiles of 32)
  const int b = blockIdx.z;
  const int i = threadIdx.x >> 5, j = threadIdx.x & 31;
  const float* ip = x1 + (size_t)b * 524288 + (size_t)(mt * 32) * 1024 + ft * 32;
#pragma unroll
  for (int s = 0; s < 4; ++s) {
    float v = ip[(size_t)(i + s * 8) * 1024 + j];
    tile[i + s * 8][j] = v;
    x1b[(size_t)(b * 512 + mt * 32 + i + s * 8) * 1024 + ft * 32 + j] = __float2bfloat16(v);
  }
  __syncthreads();
  const int h = ft >> 2, d0 = (ft & 3) * 32;
  bf16* op = VT + (size_t)(b * 8 + h) * 65536 + (size_t)d0 * 512 + mt * 32;
#pragma unroll
  for (int s = 0; s < 4; ++s)
    op[(size_t)(i + s * 8) * 512 + j] = __float2bfloat16(tile[j][i + s * 8]);
}

// ---------------- generic 32x32-tiled transpose f32 -> bf16 (weights only) -------
__global__ __launch_bounds__(256) void transpose_f32_bf16(
    const float* __restrict__ in, bf16* __restrict__ out,
    int in_rstride, int out_rstride, int hi_shift,
    long hi_mul, long lo_mul, long out_mul) {
  __shared__ float tile[32][33];
  const int z = blockIdx.z;
  const long in_off = (long)(z >> hi_shift) * hi_mul + (long)(z & ((1 << hi_shift) - 1)) * lo_mul;
  const int r0 = blockIdx.x * 32, c0 = blockIdx.y * 32;
  const int i = threadIdx.x >> 5, j = threadIdx.x & 31;
  const float* ip = in + in_off + (long)r0 * in_rstride + c0;
#pragma unroll
  for (int s = 0; s < 4; ++s) tile[i + s * 8][j] = ip[(long)(i + s * 8) * in_rstride + j];
  __syncthreads();
  bf16* op = out + (long)z * out_mul + (long)c0 * out_rstride + r0;
#pragma unroll
  for (int s = 0; s < 4; ++s) op[(long)(i + s * 8) * out_rstride + j] = __float2bfloat16(tile[j][i + s * 8]);
}

// ---------------- mask bit-pack: word[row][lr] bit mt = (mask[row][mt*16+lr] != 0)
__global__ __launch_bounds__(256) void maskpack(const int* __restrict__ mask,
                                                unsigned* __restrict__ mp) {
  __shared__ int rb[4][512];
  const int w = threadIdx.x >> 6, lane = threadIdx.x & 63;
  const int row = blockIdx.x * 4 + w;  // 0..16383 (= b*512 + n)
  const int4* src = (const int4*)(mask + (size_t)row * 512);
  int4 a = src[lane * 2], c = src[lane * 2 + 1];
  *(int4*)&rb[w][lane * 8] = a;
  *(int4*)&rb[w][lane * 8 + 4] = c;
  __syncthreads();
  if (lane < 16) {
    unsigned wd = 0;
#pragma unroll
    for (int mt = 0; mt < 32; ++mt) wd |= (rb[w][mt * 16 + lane] ? 1u : 0u) << mt;
    mp[(size_t)row * 16 + lane] = wd;
  }
}

// ---------------- m97-structure GEMM-NT (unchanged from r2) ----------------------
template <int EPI>
__global__ __launch_bounds__(256) void gemm_nt(
    const bf16* __restrict__ A, const bf16* __restrict__ BT, void* __restrict__ Op,
    const float* __restrict__ e1, const float* __restrict__ e2) {
  __shared__ alignas(16) bf16 As[128 * 32];
  __shared__ alignas(16) bf16 Bs[128 * 32];
  const int t = threadIdx.x;
  const int lane = t & 63;
  const int wv = t >> 6;
  const int wr = wv >> 1, wc = wv & 1;
  const int lr = lane & 15, g = lane >> 4;
  const int o = blockIdx.x;
  const int wk = (o & 7) * 128 + (o >> 3);
  const int m0 = (wk >> 3) * 128, n0 = (wk & 7) * 128;

  const int cr = lane >> 2;
  const int q = (lane & 3) ^ ((lane >> 3) & 3);
  const int c0 = 2 * wv, c1 = 2 * wv + 1;
  const bf16* gA0 = A + (size_t)(m0 + c0 * 16 + cr) * 1024 + q * 8;
  const bf16* gA1 = A + (size_t)(m0 + c1 * 16 + cr) * 1024 + q * 8;
  const bf16* gB0 = BT + (size_t)(n0 + c0 * 16 + cr) * 1024 + q * 8;
  const bf16* gB1 = BT + (size_t)(n0 + c1 * 16 + cr) * 1024 + q * 8;
  bf16* lA0 = &As[c0 * 512]; bf16* lA1 = &As[c1 * 512];
  bf16* lB0 = &Bs[c0 * 512]; bf16* lB1 = &Bs[c1 * 512];

  f4v acc[4][4];
#pragma unroll
  for (int i = 0; i < 4; ++i)
#pragma unroll
    for (int j = 0; j < 4; ++j) acc[i][j] = (f4v){0.f, 0.f, 0.f, 0.f};

  const int xr = (lr >> 1) & 3;

  for (int k0 = 0; k0 < 1024; k0 += 32) {
    __syncthreads();
    gload16(gA0 + k0, lA0);
    gload16(gA1 + k0, lA1);
    gload16(gB0 + k0, lB0);
    gload16(gB1 + k0, lB1);
    __syncthreads();
    s8v af[4], bfr[4];
#pragma unroll
    for (int mi = 0; mi < 4; ++mi)
      af[mi] = *reinterpret_cast<const s8v*>(&As[(wr * 64 + mi * 16 + lr) * 32 + ((g ^ xr) * 8)]);
#pragma unroll
    for (int ni = 0; ni < 4; ++ni)
      bfr[ni] = *reinterpret_cast<const s8v*>(&Bs[(wc * 64 + ni * 16 + lr) * 32 + ((g ^ xr) * 8)]);
#pragma unroll
    for (int mi = 0; mi < 4; ++mi)
#pragma unroll
      for (int ni = 0; ni < 4; ++ni)
        acc[mi][ni] = __builtin_amdgcn_mfma_f32_16x16x32_bf16(af[mi], bfr[ni], acc[mi][ni], 0, 0, 0);
  }

#pragma unroll
  for (int mi = 0; mi < 4; ++mi) {
#pragma unroll
    for (int ni = 0; ni < 4; ++ni) {
#pragma unroll
      for (int v = 0; v < 4; ++v) {
        int row = m0 + wr * 64 + mi * 16 + g * 4 + v;
        int col = n0 + wc * 64 + ni * 16 + lr;
        float val = acc[mi][ni][v];
        if constexpr (EPI == 0) {
          float qv = (val + e1[col]) * e2[(row >> 9) * 1024 + col];
          reinterpret_cast<bf16*>(Op)[(size_t)row * 1024 + col] = __float2bfloat16(qv);
        } else {
          float r2 = fmaxf(val + e1[col], 0.f) + e2[(size_t)row * 1024 + col];
          reinterpret_cast<float*>(Op)[(size_t)row * 1024 + col] = r2;
        }
      }
    }
  }
}

// ---------------- fused scores + mask + softmax + PV (v3) ------------------------
// 4 waves/block; block = (b,h, 64-row strip); wave owns 16 rows.
// K and V staged cooperatively into 2x16KB LDS chunks (gload_lds, source-side XOR
// swizzle -> conflict-free ds_read_b128), stage-ahead double-buffer, 1 barrier/chunk.
// PV reads P back from the just-written att rows (own-XCD L2) after a drain barrier.
__global__ __launch_bounds__(256) void attn_fused(
    const bf16* __restrict__ Qs, const bf16* __restrict__ x1b,
    const bf16* __restrict__ VT, const unsigned* __restrict__ mp,
    float* __restrict__ att, bf16* __restrict__ Vout) {
  __shared__ alignas(16) bf16 stage[2][8192];   // 2 x 16KB
  const int o = blockIdx.x;                      // 2048 blocks
  const int wk = (o & 7) * 256 + (o >> 3);       // XCD c owns bh in [c*32, c*32+32)
  const int rt = wk & 7, bh = wk >> 3;
  const int h = bh & 7, b = bh >> 3;
  const int w = threadIdx.x >> 6;
  const int lane = threadIdx.x & 63;
  const int lr = lane & 15, g = lane >> 4;
  const int n0 = rt * 64 + w * 16;               // this wave's 16 rows

  const bf16* kbase = x1b + (size_t)b * 524288 + h * 128;
  const bf16* vbase = VT + (size_t)bh * 65536;
  const int ks = lane & 15;        // K stage slot
  const int vs = lane & 7;         // V stage slot
  const int xf = lr & 7;           // read-side xor factor

  // Q fragments (global, once)
  const bf16* qrow = Qs + (size_t)(b * 512 + n0 + lr) * 1024 + h * 128;
  s8v qa[4];
#pragma unroll
  for (int kt = 0; kt < 4; ++kt) qa[kt] = *reinterpret_cast<const s8v*>(qrow + kt * 32 + g * 8);

  // mask words (bit mt = masked at col mt*16+lr), one per owned row
  unsigned mw[4];
#pragma unroll
  for (int v = 0; v < 4; ++v)
    mw[v] = mp[(size_t)(b * 512 + n0 + g * 4 + v) * 16 + lr];

  f4v acc[32];
#pragma unroll
  for (int mt = 0; mt < 32; ++mt) acc[mt] = (f4v){0.f, 0.f, 0.f, 0.f};

  // LDS[r][s] = K[ck*64+r][ (s^(r&7))*8 .. +8 ]   (rows of 16 slots x 16B)
  auto STAGE_K = [&](int ck, int bufi) {
#pragma unroll
    for (int i = 0; i < 4; ++i) {
      int r = (w * 4 + i) * 4 + (lane >> 4);
      const bf16* src = kbase + (size_t)(ck * 64 + r) * 1024 + ((ks ^ (r & 7)) * 8);
      gload16(src, &stage[bufi][(w * 4 + i) * 512]);
    }
  };
  // LDS[d][s] = VT[d][ cv*64 + (s^(d&7))*8 .. +8 ] (rows of 8 slots x 16B)
  auto STAGE_V = [&](int cv, int bufi) {
#pragma unroll
    for (int i = 0; i < 4; ++i) {
      int d = (w * 4 + i) * 8 + (lane >> 3);
      const bf16* src = vbase + (size_t)d * 512 + cv * 64 + ((vs ^ (d & 7)) * 8);
      gload16(src, &stage[bufi][(w * 4 + i) * 512]);
    }
  };

  // --- QK^T over 8 K-chunks ---
  STAGE_K(0, 0);
  __syncthreads();
#pragma unroll
  for (int t = 0; t < 8; ++t) {
    if (t < 7) STAGE_K(t + 1, (t + 1) & 1);
    else       STAGE_V(0, 0);
    const bf16* bufp = stage[t & 1];
#pragma unroll
    for (int mtl = 0; mtl < 4; ++mtl) {
#pragma unroll
      for (int kt = 0; kt < 4; ++kt) {
        s8v bb = *reinterpret_cast<const s8v*>(
            bufp + (mtl * 16 + lr) * 128 + (((kt * 4 + g) ^ xf) * 8));
        acc[t * 4 + mtl] =
            __builtin_amdgcn_mfma_f32_16x16x32_bf16(qa[kt], bb, acc[t * 4 + mtl], 0, 0, 0);
      }
    }
    __syncthreads();   // drains this iter's stage; protects buffer swap
  }
  STAGE_V(1, 1);       // overlaps softmax

  // --- mask + softmax (rows g*4+v, cols mt*16+lr) ---
  float mx[4] = {-3e38f, -3e38f, -3e38f, -3e38f};
#pragma unroll
  for (int mt = 0; mt < 32; ++mt) {
#pragma unroll
    for (int v = 0; v < 4; ++v) {
      float val = acc[mt][v];
      val = ((mw[v] >> mt) & 1u) ? -1e9f : val;
      acc[mt][v] = val;
      mx[v] = fmaxf(mx[v], val);
    }
  }
#pragma unroll
  for (int v = 0; v < 4; ++v) {
    float m = mx[v];
    m = fmaxf(m, __shfl_xor(m, 1));
    m = fmaxf(m, __shfl_xor(m, 2));
    m = fmaxf(m, __shfl_xor(m, 4));
    m = fmaxf(m, __shfl_xor(m, 8));
    mx[v] = m;
  }
  float sm[4] = {0.f, 0.f, 0.f, 0.f};
#pragma unroll
  for (int mt = 0; mt < 32; ++mt) {
#pragma unroll
    for (int v = 0; v < 4; ++v) {
      float e = __expf(acc[mt][v] - mx[v]);
      acc[mt][v] = e;
      sm[v] += e;
    }
  }
#pragma unroll
  for (int v = 0; v < 4; ++v) {
    float s = sm[v];
    s += __shfl_xor(s, 1);
    s += __shfl_xor(s, 2);
    s += __shfl_xor(s, 4);
    s += __shfl_xor(s, 8);
    sm[v] = 1.0f / s;
  }

  // --- att store (f32, required output) ---
  float* orow = att + ((size_t)bh * 512 + n0) * 512;
#pragma unroll
  for (int mt = 0; mt < 32; ++mt) {
#pragma unroll
    for (int v = 0; v < 4; ++v)
      orow[(g * 4 + v) * 512 + mt * 16 + lr] = acc[mt][v] * sm[v];
  }
  __syncthreads();   // drains att stores (and V1 stage) before P readback

  // --- PV over 8 V-chunks; P-frags read back from att (L2-hot) ---
  f4v oacc[8];
#pragma unroll
  for (int nt = 0; nt < 8; ++nt) oacc[nt] = (f4v){0.f, 0.f, 0.f, 0.f};
  const float* attq = att + ((size_t)bh * 512 + n0 + lr) * 512;

#pragma unroll
  for (int c = 0; c < 8; ++c) {
    if (c >= 1 && c < 7) STAGE_V(c + 1, (c + 1) & 1);
    const bf16* bufp = stage[c & 1];
    s8v pa[2];
#pragma unroll
    for (int j = 0; j < 2; ++j) {
      int kt = c * 2 + j;
      f4v lo = *reinterpret_cast<const f4v*>(attq + kt * 32 + g * 8);
      f4v hi = *reinterpret_cast<const f4v*>(attq + kt * 32 + g * 8 + 4);
      s8v p;
      p[0] = (short)f2b(lo.x); p[1] = (short)f2b(lo.y);
      p[2] = (short)f2b(lo.z); p[3] = (short)f2b(lo.w);
      p[4] = (short)f2b(hi.x); p[5] = (short)f2b(hi.y);
      p[6] = (short)f2b(hi.z); p[7] = (short)f2b(hi.w);
      pa[j] = p;
    }
#pragma unroll
    for (int nt = 0; nt < 8; ++nt) {
#pragma unroll
      for (int j = 0; j < 2; ++j) {
        s8v bb = *reinterpret_cast<const s8v*>(
            bufp + (nt * 16 + lr) * 64 + (((j * 4 + g) ^ xf) * 8));
        oacc[nt] = __builtin_amdgcn_mfma_f32_16x16x32_bf16(pa[j], bb, oacc[nt], 0, 0, 0);
      }
    }
    __syncthreads();
  }

  // --- Vout epilogue (in-place over Qs; only this wave reads these elements) ---
#pragma unroll
  for (int nt = 0; nt < 8; ++nt) {
#pragma unroll
    for (int v = 0; v < 4; ++v) {
      Vout[(size_t)(b * 512 + n0 + g * 4 + v) * 1024 + h * 128 + nt * 16 + lr] =
          __float2bfloat16(oacc[nt][v]);
    }
  }
}

extern "C" void kernel_launch(void* const* d_in, const int* in_sizes, int n_in,
                              void* d_out, int out_size, void* d_ws, size_t ws_size,
                              hipStream_t stream) {
  (void)in_sizes; (void)n_in; (void)out_size; (void)ws_size;
  const float* x1 = (const float*)d_in[0];
  const float* x2 = (const float*)d_in[1];
  // d_in[2]=adj, d_in[3]=bias are unused by the reference forward
  const int* mask = (const int*)d_in[4];
  const float* Wq = (const float*)d_in[5];
  const float* bq = (const float*)d_in[6];
  const float* Wl = (const float*)d_in[7];
  const float* bl = (const float*)d_in[8];

  float* xout = (float*)d_out;                  // [32,512,1024]
  float* att = (float*)d_out + 16777216;        // [32,8,512,512]

  char* ws = (char*)d_ws;
  bf16* x1b   = (bf16*)(ws);                    // 33.5MB  K source (bf16 x1)
  bf16* VT    = (bf16*)(ws + 33554432);         // 33.5MB  [B,H,128,512]
  bf16* Qs    = (bf16*)(ws + 67108864);         // 33.5MB  gated Q; reused in-place as V_
  bf16* WcatT = (bf16*)(ws + 100663296);        // 2MB     [1024][1024]; reused as mp after gemm<0>
  bf16* WlT   = (bf16*)(ws + 102760448);        // 2MB     [1024][1024]
  float* g2s  = (float*)(ws + 104857600);       // 128KB   [B][1024]
  unsigned* mp = (unsigned*)WcatT;              // 1MB     [32*512][16] packed mask

  gate_kernel<<<dim3(32 * 16), dim3(256), 0, stream>>>(x2, g2s);
  x1prep<<<dim3(16, 32, 32), dim3(256), 0, stream>>>(x1, x1b, VT);
  // WcatT[h*128+d][f] = Wq[h][f][d]
  transpose_f32_bf16<<<dim3(32, 4, 8), dim3(256), 0, stream>>>(
      Wq, WcatT, 128, 1024, 0, (long)131072, (long)0, (long)131072);
  // WlT[n][k] = Wl[k][n]
  transpose_f32_bf16<<<dim3(32, 32, 1), dim3(256), 0, stream>>>(
      Wl, WlT, 1024, 1024, 0, (long)0, (long)0, (long)0);
  // Qs = (x1 @ Wcat + bq) * g2s
  gemm_nt<0><<<dim3(1024), dim3(256), 0, stream>>>(x1b, WcatT, (void*)Qs, bq, g2s);
  // pack mask into WcatT region (free after gemm<0>)
  maskpack<<<dim3(4096), dim3(256), 0, stream>>>(mask, mp);
  // scores + mask + softmax -> att (d_out), then PV -> Vout (in-place over Qs)
  attn_fused<<<dim3(2048), dim3(256), 0, stream>>>(Qs, x1b, VT, mp, att, Qs);
  // xout = relu(V_ @ Wl + bl) + x1
  gemm_nt<2><<<dim3(1024), dim3(256), 0, stream>>>(Qs, WlT, (void*)xout, bl, x1);
}